// Round 5
// baseline (449.068 us; speedup 1.0000x reference)
//
#include <hip/hip_runtime.h>
#include <hip/hip_bf16.h>

// MultiScaleFeatureExtractor on MI355X (gfx950) — Round 5
// Math restructuring (unchanged):
//   logits = x @ (Wx@Wslice) + (bx@Wslice + bslice)      (px never materialized)
//   out[s,d] = (sum_n w[n,s]*fx[n,d]) / (sum_n w[n,s] + 0.01)
// R5 vs R4 (both changes counter-driven):
//   - R4's VGPR_Count=120 proved weight frags were NOT register-resident: the
//     compiler re-loaded them from L2 every chunk -> 4.2 GB L2 traffic ~= the
//     entire 137us main duration. Fix: pin wfr via empty asm ("+v") after load.
//   - xprep + 64MB xf buffer deleted: A-fragments map to contiguous 128B fp32
//     row segments of x, so main loads fp32 directly + v_cvt_pk_bf16_f32.
//     (non-main was a stubborn ~206us across R2-R4; xprep implicated.)
//   - tile=512 tokens (2048 blocks x 16 chunks): halves Tg atomic traffic,
//     amortizes the 64KB/block weight prologue.
//
// ws layout (NEED = 792,576 B):
//   [0,      524288) WtF  bf16 B-frags [proj(2)][head(8)][nt(4)][ks(8)][lane(64)][j(8)]
//   [524288, 526336) bc   f32 [512]
//   [526336, 788480) Tg   f32 [B*8*64*64]
//   [788480, 792576) ng   f32 [B*8*64]

typedef __attribute__((ext_vector_type(8))) short short8;
typedef __attribute__((ext_vector_type(4))) short short4v;
typedef __attribute__((ext_vector_type(4))) float float4v;
typedef __attribute__((ext_vector_type(2))) unsigned int uint2v;

#define MP 36        // wT/fT pitch: 32-token rows + 4 pad shorts (72B rows, conflict-free: R4 measured 0)

__device__ __forceinline__ unsigned short f2bf(float f) {
    union { float f; unsigned int u; } v; v.f = f;
    unsigned int r = (v.u + 0x7FFFu + ((v.u >> 16) & 1u)) >> 16;  // RNE
    return (unsigned short)r;
}

__device__ __forceinline__ unsigned int pack2(float a, float b) {
    __hip_bfloat162 h = __float22bfloat162_rn(float2{a, b});
    union { __hip_bfloat162 h; unsigned int u; } cv; cv.h = h;
    return cv.u;   // low 16 = a, high 16 = b
}

// ---- prep3: fold Wx@Wslice + reformat Wfx into B-frag order; compute bc. (R4, verified)
__global__ __launch_bounds__(256)
void msfe_prep3(const float* __restrict__ Wx, const float* __restrict__ bx,
                const float* __restrict__ Wfx,
                const float* __restrict__ Wslice, const float* __restrict__ bslice,
                unsigned short* __restrict__ WtF, float* __restrict__ bcv) {
    const int b = blockIdx.x, t = threadIdx.x;
    if (b < 32) {
        const int head = b >> 2, kq = (b >> 1) & 1, sg = b & 1;
        __shared__ float Wsl[64 * 68];
        __shared__ unsigned short stg[128 * 33];
        #pragma unroll
        for (int i = 0; i < 16; ++i) {
            int idx = i * 256 + t; int d = idx >> 6, s = idx & 63;
            Wsl[d * 68 + s] = Wslice[idx];
        }
        const int kl = t & 127, sHalf = t >> 7;
        const int k = kq * 128 + kl;
        float wxr[64];
        const float4v* src = (const float4v*)(Wx + (long)k * 512 + head * 64);
        #pragma unroll
        for (int i = 0; i < 16; ++i) {
            float4v v = src[i];
            wxr[i*4+0] = v.x; wxr[i*4+1] = v.y; wxr[i*4+2] = v.z; wxr[i*4+3] = v.w;
        }
        __syncthreads();
        const int sbase = sg * 32 + sHalf * 16;
        float acc[16];
        #pragma unroll
        for (int si = 0; si < 16; ++si) acc[si] = 0.f;
        #pragma unroll
        for (int d = 0; d < 64; ++d) {
            float w = wxr[d];
            const float4v* r4 = (const float4v*)(Wsl + d * 68 + sbase);
            float4v v0 = r4[0], v1 = r4[1], v2 = r4[2], v3 = r4[3];
            acc[0]  += w * v0.x; acc[1]  += w * v0.y; acc[2]  += w * v0.z; acc[3]  += w * v0.w;
            acc[4]  += w * v1.x; acc[5]  += w * v1.y; acc[6]  += w * v1.z; acc[7]  += w * v1.w;
            acc[8]  += w * v2.x; acc[9]  += w * v2.y; acc[10] += w * v2.z; acc[11] += w * v2.w;
            acc[12] += w * v3.x; acc[13] += w * v3.y; acc[14] += w * v3.z; acc[15] += w * v3.w;
        }
        #pragma unroll
        for (int si = 0; si < 16; ++si)
            stg[kl * 33 + sHalf * 16 + si] = f2bf(acc[si]);
        __syncthreads();
        #pragma unroll
        for (int i = 0; i < 2; ++i) {
            int e = i * 256 + t;
            int ntL = e >> 8, ksL = (e >> 6) & 3, lane = e & 63;
            int quad = lane >> 4, l16 = lane & 15;
            int nt = sg * 2 + ntL;
            int ks = kq * 4 + ksL;
            short8 o;
            #pragma unroll
            for (int j = 0; j < 8; ++j) {
                int kl2 = ksL * 32 + quad * 8 + j;
                o[j] = (short)stg[kl2 * 33 + ntL * 16 + l16];
            }
            *(short8*)(WtF + ((((long)(0 * 8 + head) * 4 + nt) * 8 + ks) * 64 + lane) * 8) = o;
        }
    } else if (b < 48) {
        const int head = (b - 32) >> 1, kq = (b - 32) & 1;
        #pragma unroll
        for (int i = 0; i < 4; ++i) {
            int e = i * 256 + t;
            int nt = e >> 8, ksL = (e >> 6) & 3, lane = e & 63;
            int quad = lane >> 4, l16 = lane & 15;
            int ks = kq * 4 + ksL;
            int col = head * 64 + nt * 16 + l16;
            short8 o;
            #pragma unroll
            for (int j = 0; j < 8; ++j) {
                int k = kq * 128 + ksL * 32 + quad * 8 + j;
                o[j] = (short)f2bf(Wfx[(long)k * 512 + col]);
            }
            *(short8*)(WtF + ((((long)(1 * 8 + head) * 4 + nt) * 8 + ks) * 64 + lane) * 8) = o;
        }
    } else {
        #pragma unroll
        for (int p = 0; p < 2; ++p) {
            int j = t + p * 256;
            int h = j >> 6, s = j & 63;
            float bsum = bslice[s];
            for (int d = 0; d < 64; ++d) bsum += bx[h * 64 + d] * Wslice[d * 64 + s];
            bcv[j] = bsum;
        }
    }
}

// ---- main4: 2048 blocks x 256 thr (4 waves), 512-token tiles, 16 x 32-token chunks.
// Weights pinned in registers; A-frags converted from fp32 x on the fly.
__global__ __launch_bounds__(256, 2)
void msfe_main4(const float* __restrict__ x,
                const unsigned short* __restrict__ WtF,
                const float* __restrict__ bcv,
                const float* __restrict__ bfx,
                const float* __restrict__ temperature,
                float* __restrict__ Tg, float* __restrict__ ng) {
    __shared__ unsigned short wT[2][64 * MP];   // [s][token] bf16, double-buffered
    __shared__ unsigned short fT[2][64 * MP];   // [d][token]

    const int tid  = threadIdx.x;
    const int lane = tid & 63;
    const int wv   = tid >> 6;    // 0..3
    const int quad = lane >> 4;
    const int l16  = lane & 15;

    // swizzle: blocks landing on one XCD in a dispatch round = 8 heads of one tile
    const int bidx = blockIdx.x;                     // 0..2047
    const int tile = (bidx >> 6) * 8 + (bidx & 7);   // 0..255 (512 tokens each)
    const int head = (bidx >> 3) & 7;
    const int batch = tile >> 7;

    const int proj = wv >> 1;   // waves 0,1: logits+softmax; 2,3: fx
    const int tw   = wv & 1;    // 16-token sub-tile within 32-token chunk

    // ---- weight fragments -> registers, PINNED (R4: compiler re-loaded them
    // from L2 every chunk = 4.2GB traffic; asm output can't be rematerialized)
    short8 wfr[4][8];
    {
        const unsigned short* wb = WtF + (((long)(proj * 8 + head) * 4) * 8) * 512 + (long)lane * 8;
        #pragma unroll
        for (int nt = 0; nt < 4; ++nt)
            #pragma unroll
            for (int ks = 0; ks < 8; ++ks)
                wfr[nt][ks] = *(const short8*)(wb + (nt * 8 + ks) * 512);
    }
    #pragma unroll
    for (int nt = 0; nt < 4; ++nt)
        #pragma unroll
        for (int ks = 0; ks < 8; ++ks)
            asm volatile("" : "+v"(wfr[nt][ks]));

    float bias[4];
    #pragma unroll
    for (int nt = 0; nt < 4; ++nt)
        bias[nt] = (proj == 0 ? bcv : bfx)[head * 64 + nt * 16 + l16];
    float tmp = temperature[head];
    tmp = fminf(fmaxf(tmp, 0.5f), 5.0f);
    const float invt = 1.0f / tmp;

    float4v Tac[4];
    #pragma unroll
    for (int nt = 0; nt < 4; ++nt) Tac[nt] = (float4v){0.f, 0.f, 0.f, 0.f};
    float normAcc[4] = {0.f, 0.f, 0.f, 0.f};

    // A-frags direct from fp32 x: lane(quad,l16) reads row l16, 8 ch at ks*32+quad*8
    // -> per instr the wave touches 16 contiguous 128B segments (full 64B granules)
    const float* xrow = x + ((long)tile * 512 + tw * 16 + l16) * 256;
    short8 afr[8];
    #pragma unroll
    for (int ks = 0; ks < 8; ++ks) {
        const float4v* p = (const float4v*)(xrow + ks * 32 + quad * 8);
        float4v v0 = p[0], v1 = p[1];
        union { short8 s; unsigned int u[4]; } cu;
        cu.u[0] = pack2(v0.x, v0.y); cu.u[1] = pack2(v0.z, v0.w);
        cu.u[2] = pack2(v1.x, v1.y); cu.u[3] = pack2(v1.z, v1.w);
        afr[ks] = cu.s;
    }

    for (int c = 0; c < 16; ++c) {
        const int wbuf = c & 1, rbuf = wbuf ^ 1;

        // P1: [16 tok x 64 cols] += A(x) * B(w-regs), K=256
        float4v acc[4];
        #pragma unroll
        for (int nt = 0; nt < 4; ++nt) acc[nt] = (float4v){0.f, 0.f, 0.f, 0.f};
        #pragma unroll
        for (int ks = 0; ks < 8; ++ks) {
            #pragma unroll
            for (int nt = 0; nt < 4; ++nt)
                acc[nt] = __builtin_amdgcn_mfma_f32_16x16x32_bf16(afr[ks], wfr[nt][ks], acc[nt], 0, 0, 0);
        }

        // prefetch+convert next chunk's A-frags (hidden behind P3+P2+barrier)
        if (c < 15) {
            #pragma unroll
            for (int ks = 0; ks < 8; ++ks) {
                const float4v* p = (const float4v*)(xrow + (long)(c + 1) * 8192 + ks * 32 + quad * 8);
                float4v v0 = p[0], v1 = p[1];
                union { short8 s; unsigned int u[4]; } cu;
                cu.u[0] = pack2(v0.x, v0.y); cu.u[1] = pack2(v0.z, v0.w);
                cu.u[2] = pack2(v1.x, v1.y); cu.u[3] = pack2(v1.z, v1.w);
                afr[ks] = cu.s;
            }
        }

        // P3 (skewed): T[s][d] += w^T fx over PREVIOUS chunk's 32 tokens.
        if (c > 0) {
            short8 a = *(const short8*)(&wT[rbuf][(wv * 16 + l16) * MP + quad * 8]);
            #pragma unroll
            for (int nt = 0; nt < 4; ++nt) {
                short8 bf = *(const short8*)(&fT[rbuf][(nt * 16 + l16) * MP + quad * 8]);
                Tac[nt] = __builtin_amdgcn_mfma_f32_16x16x32_bf16(a, bf, Tac[nt], 0, 0, 0);
            }
        }

        // P2: softmax / bias -> transposed bf16 into wbuf.
        // C layout: col=l16+16*nt, row=quad*4+rr -> token = tw*16+quad*4+rr
        if (proj == 0) {
            float e[4][4];
            #pragma unroll
            for (int nt = 0; nt < 4; ++nt)
                #pragma unroll
                for (int rr = 0; rr < 4; ++rr)
                    e[nt][rr] = __expf((acc[nt][rr] + bias[nt]) * invt);  // bounded arg, shift-free
            #pragma unroll
            for (int rr = 0; rr < 4; ++rr) {
                float s = e[0][rr] + e[1][rr] + e[2][rr] + e[3][rr];
                s += __shfl_xor(s, 1); s += __shfl_xor(s, 2);
                s += __shfl_xor(s, 4); s += __shfl_xor(s, 8);
                float inv = 1.0f / s;
                e[0][rr] *= inv; e[1][rr] *= inv; e[2][rr] *= inv; e[3][rr] *= inv;
            }
            #pragma unroll
            for (int nt = 0; nt < 4; ++nt) {
                normAcc[nt] += e[nt][0] + e[nt][1] + e[nt][2] + e[nt][3];
                uint2v p;
                p.x = pack2(e[nt][0], e[nt][1]);
                p.y = pack2(e[nt][2], e[nt][3]);
                *(uint2v*)(&wT[wbuf][(nt * 16 + l16) * MP + tw * 16 + quad * 4]) = p;
            }
        } else {
            #pragma unroll
            for (int nt = 0; nt < 4; ++nt) {
                uint2v p;
                p.x = pack2(acc[nt][0] + bias[nt], acc[nt][1] + bias[nt]);
                p.y = pack2(acc[nt][2] + bias[nt], acc[nt][3] + bias[nt]);
                *(uint2v*)(&fT[wbuf][(nt * 16 + l16) * MP + tw * 16 + quad * 4]) = p;
            }
        }

        __syncthreads();   // single barrier per chunk
    }

    // final P3 on the last written buffer (chunk 15 -> buf 1)
    {
        short8 a = *(const short8*)(&wT[1][(wv * 16 + l16) * MP + quad * 8]);
        #pragma unroll
        for (int nt = 0; nt < 4; ++nt) {
            short8 bf = *(const short8*)(&fT[1][(nt * 16 + l16) * MP + quad * 8]);
            Tac[nt] = __builtin_amdgcn_mfma_f32_16x16x32_bf16(a, bf, Tac[nt], 0, 0, 0);
        }
    }

    // epilogue: atomics into global accumulators
    const int basehs = (batch * 8 + head) * 64;
    #pragma unroll
    for (int nt = 0; nt < 4; ++nt) {
        #pragma unroll
        for (int rr = 0; rr < 4; ++rr) {
            int s = wv * 16 + quad * 4 + rr;
            int d = nt * 16 + l16;
            atomicAdd(&Tg[(basehs + s) * 64 + d], Tac[nt][rr]);
        }
    }
    if (proj == 0) {
        #pragma unroll
        for (int nt = 0; nt < 4; ++nt) {
            float v = normAcc[nt];
            v += __shfl_xor(v, 16);
            v += __shfl_xor(v, 32);
            if (quad == 0) atomicAdd(&ng[basehs + nt * 16 + l16], v);
        }
    }
}

// ---------------- finalize ----------------
__global__ void msfe_final(const float* __restrict__ Tg, const float* __restrict__ ng,
                           float* __restrict__ out) {
    int i = blockIdx.x * 256 + threadIdx.x;
    out[i] = Tg[i] / (ng[i >> 6] + 0.01f);
}

extern "C" void kernel_launch(void* const* d_in, const int* in_sizes, int n_in,
                              void* d_out, int out_size, void* d_ws, size_t ws_size,
                              hipStream_t stream) {
    const float* x       = (const float*)d_in[0];
    const float* Wx      = (const float*)d_in[1];
    const float* bx      = (const float*)d_in[2];
    const float* Wfx     = (const float*)d_in[3];
    const float* bfx     = (const float*)d_in[4];
    const float* Wslice  = (const float*)d_in[5];
    const float* bslice  = (const float*)d_in[6];
    const float* temp    = (const float*)d_in[7];

    char* ws = (char*)d_ws;
    unsigned short* WtF = (unsigned short*)ws;      // 524,288 B
    float* bc = (float*)(ws + 524288);              //   2,048 B
    float* Tg = (float*)(ws + 526336);              // 262,144 B
    float* ng = (float*)(ws + 788480);              //   4,096 B

    hipMemsetAsync(Tg, 0, 262144 + 4096, stream);   // ws is re-poisoned 0xAA each call
    msfe_prep3<<<49, 256, 0, stream>>>(Wx, bx, Wfx, Wslice, bslice, WtF, bc);
    msfe_main4<<<2048, 256, 0, stream>>>(x, WtF, bc, bfx, temp, Tg, ng);
    msfe_final<<<256, 256, 0, stream>>>(Tg, ng, (float*)d_out);
}

// Round 6
// 337.387 us; speedup vs baseline: 1.3310x; 1.3310x over previous
//
#include <hip/hip_runtime.h>
#include <hip/hip_bf16.h>

// MultiScaleFeatureExtractor on MI355X (gfx950) — Round 6
// Math restructuring (unchanged):
//   logits = x @ (Wx@Wslice) + (bx@Wslice + bslice)      (px never materialized)
//   out[s,d] = (sum_n w[n,s]*fx[n,d]) / (sum_n w[n,s] + 0.01)
// R6 vs R5 (counter-driven):
//   - R5 post-mortem: "+v" pin put all 128 weight regs in the VGPR pool
//     (VGPR_Count=128) and the fp32 direct-load path starved -> latency-bound
//     307us. Fix: weights pinned in AGPRs ("+a") — MFMA reads B from AGPR
//     natively on gfx950 (unified RF), VGPRs freed for load pipelining —
//     and A-frags restored to the bf16 xf path (R4's coalesced b128 loads,
//     zero conversion registers in main).
//   - prep3 was ~115us (49 latency-bound blocks). prep4: 321 blocks,
//     LDS-staged Wslice/Wx, coalesced everywhere, <=8 outputs/thread.
//   - xprep unchanged (R4 version, ~64us measured by subtraction).
//
// ws layout (NEED = 67,901,440 B):
//   [0,        67108864)  xf   bf16 A-frags [g32(4096)][tw(2)][ks(8)][lane(64)][j(8)]
//                              (g32 = global 32-token chunk index)
//   [67108864, 67633152)  WtF  bf16 B-frags [proj(2)][head(8)][nt(4)][ks(8)][lane(64)][j(8)]
//   [67633152, 67635200)  bc   f32 [512]
//   [67635200, 67897344)  Tg   f32 [B*8*64*64]
//   [67897344, 67901440)  ng   f32 [B*8*64]

typedef __attribute__((ext_vector_type(8))) short short8;
typedef __attribute__((ext_vector_type(4))) short short4v;
typedef __attribute__((ext_vector_type(4))) float float4v;
typedef __attribute__((ext_vector_type(2))) unsigned int uint2v;

#define WPITCH 264   // xprep LDS pitch (shorts)
#define MP 36        // wT/fT pitch: 32-token rows + 4 pad shorts (R4 measured 0 conflicts)

__device__ __forceinline__ unsigned short f2bf(float f) {
    union { float f; unsigned int u; } v; v.f = f;
    unsigned int r = (v.u + 0x7FFFu + ((v.u >> 16) & 1u)) >> 16;  // RNE
    return (unsigned short)r;
}

__device__ __forceinline__ unsigned int pack2(float a, float b) {
    __hip_bfloat162 h = __float22bfloat162_rn(float2{a, b});
    union { __hip_bfloat162 h; unsigned int u; } cv; cv.h = h;
    return cv.u;   // low 16 = a, high 16 = b
}

// ---- xprep: fp32 x -> bf16 A-frag order. 2048 blocks x 256 thr, 64 tokens/block. (R4, verified)
__global__ __launch_bounds__(256)
void msfe_xprep(const float* __restrict__ x, unsigned short* __restrict__ xf) {
    __shared__ unsigned short Xs[64 * WPITCH];
    const int blk = blockIdx.x;
    const int tid = threadIdx.x;
    const float4v* xg = (const float4v*)(x + (long)blk * 64 * 256);
    #pragma unroll
    for (int i = 0; i < 16; ++i) {
        float4v v = xg[tid + i * 256];
        int f = (tid + i * 256) * 4;       // flat float index in 64x256 tile
        int row = f >> 8, col = f & 255;
        unsigned int lo = pack2(v.x, v.y), hi = pack2(v.z, v.w);
        *(unsigned int*)(Xs + row * WPITCH + col)     = lo;
        *(unsigned int*)(Xs + row * WPITCH + col + 2) = hi;
    }
    __syncthreads();
    const int wv = tid >> 6, lane = tid & 63;
    const int quad = lane >> 4, l16 = lane & 15;
    const int chunkL = wv >> 1, tw = wv & 1;       // block covers 2 chunks of 32 tok
    // g32 = blk*2 + chunkL; xf offset = (g32*2 + tw)*4096 + lane*8 + ks*512
    unsigned short* ob = xf + (((long)(blk * 2 + chunkL) * 2 + tw) * 4096) + (long)lane * 8;
    const int row0 = chunkL * 32 + tw * 16 + l16;
    #pragma unroll
    for (int ks = 0; ks < 8; ++ks) {
        short8 o = *(const short8*)(Xs + row0 * WPITCH + ks * 32 + quad * 8);
        *(short8*)(ob + ks * 512) = o;     // coalesced 1KB/instr
    }
}

// ---- prep4: fold Wx@Wslice + reformat Wfx into B-frag order; compute bc.
// grid 321 x 256:
//   b in [0,256):   proj0 fold. head=b>>5, oct=b&31 (c = oct*8+j, ks=oct>>2, quad=oct&3)
//   b in [256,320): proj1 reformat. head=(b-256)>>3, ks=(b-256)&7
//   b == 320:       bc
__global__ __launch_bounds__(256)
void msfe_prep4(const float* __restrict__ Wx, const float* __restrict__ bx,
                const float* __restrict__ Wfx,
                const float* __restrict__ Wslice, const float* __restrict__ bslice,
                unsigned short* __restrict__ WtF, float* __restrict__ bcv) {
    const int b = blockIdx.x, t = threadIdx.x;
    if (b < 256) {
        const int head = b >> 5, oct = b & 31;
        __shared__ float Wsl[64 * 65];          // [d][s] +1 pad
        __shared__ float WxS[8 * 64];           // [j][d]
        __shared__ unsigned short stg[8 * 64];  // [j][s]
        #pragma unroll
        for (int i = 0; i < 16; ++i) {          // Wslice: 4096 floats, coalesced
            int idx = i * 256 + t; int d = idx >> 6, s = idx & 63;
            Wsl[d * 65 + s] = Wslice[idx];
        }
        #pragma unroll
        for (int i = 0; i < 2; ++i) {           // 8 Wx rows x 64 ch, coalesced 256B rows
            int idx = i * 256 + t; int j = idx >> 6, d = idx & 63;
            WxS[j * 64 + d] = Wx[(long)(oct * 8 + j) * 512 + head * 64 + d];
        }
        __syncthreads();
        const int s = t & 63;
        #pragma unroll
        for (int rep = 0; rep < 2; ++rep) {
            int j = (t >> 6) + rep * 4;         // wave-uniform j
            float a0 = 0.f, a1 = 0.f, a2 = 0.f, a3 = 0.f;
            #pragma unroll
            for (int d = 0; d < 64; d += 4) {   // WxS broadcast (free), Wsl 2-way (free)
                a0 += WxS[j * 64 + d]     * Wsl[(d)     * 65 + s];
                a1 += WxS[j * 64 + d + 1] * Wsl[(d + 1) * 65 + s];
                a2 += WxS[j * 64 + d + 2] * Wsl[(d + 2) * 65 + s];
                a3 += WxS[j * 64 + d + 3] * Wsl[(d + 3) * 65 + s];
            }
            stg[j * 64 + s] = f2bf((a0 + a1) + (a2 + a3));
        }
        __syncthreads();
        if (t < 64) {
            int nt = t >> 4, l16 = t & 15;
            int ks = oct >> 2, quad = oct & 3;
            int lane = quad * 16 + l16;
            short8 o;
            #pragma unroll
            for (int j = 0; j < 8; ++j) o[j] = (short)stg[j * 64 + nt * 16 + l16];
            *(short8*)(WtF + ((((long)(0 * 8 + head) * 4 + nt) * 8 + ks) * 64 + lane) * 8) = o;
        }
    } else if (b < 320) {
        const int head = (b - 256) >> 3, ks = (b - 256) & 7;
        const int nt = t >> 6, lane = t & 63;
        const int quad = lane >> 4, l16 = lane & 15;
        short8 o;
        #pragma unroll
        for (int j = 0; j < 8; ++j)             // 4x64B segments per instr
            o[j] = (short)f2bf(Wfx[(long)(ks * 32 + quad * 8 + j) * 512 + head * 64 + nt * 16 + l16]);
        *(short8*)(WtF + ((((long)(1 * 8 + head) * 4 + nt) * 8 + ks) * 64 + lane) * 8) = o;
    } else {
        #pragma unroll
        for (int p = 0; p < 2; ++p) {
            int j = t + p * 256;
            int h = j >> 6, s = j & 63;
            float bsum = bslice[s];
            for (int d = 0; d < 64; ++d) bsum += bx[h * 64 + d] * Wslice[d * 64 + s];
            bcv[j] = bsum;
        }
    }
}

// ---- main5: 2048 blocks x 256 thr (4 waves), 512-token tiles, 16 x 32-token chunks.
// Weights pinned in AGPRs ("+a"); A-frags from bf16 xf (coalesced b128 loads).
__global__ __launch_bounds__(256, 2)
void msfe_main5(const unsigned short* __restrict__ xf,
                const unsigned short* __restrict__ WtF,
                const float* __restrict__ bcv,
                const float* __restrict__ bfx,
                const float* __restrict__ temperature,
                float* __restrict__ Tg, float* __restrict__ ng) {
    __shared__ unsigned short wT[2][64 * MP];   // [s][token] bf16, double-buffered
    __shared__ unsigned short fT[2][64 * MP];   // [d][token]

    const int tid  = threadIdx.x;
    const int lane = tid & 63;
    const int wv   = tid >> 6;    // 0..3
    const int quad = lane >> 4;
    const int l16  = lane & 15;

    // swizzle: a tile's 8 head-blocks land on one XCD in the same dispatch round
    const int bidx = blockIdx.x;                     // 0..2047
    const int tile = (bidx >> 6) * 8 + (bidx & 7);   // 0..255 (512 tokens each)
    const int head = (bidx >> 3) & 7;
    const int batch = tile >> 7;

    const int proj = wv >> 1;   // waves 0,1: logits+softmax; 2,3: fx
    const int tw   = wv & 1;    // 16-token sub-tile within 32-token chunk

    // ---- weight fragments -> AGPRs, pinned.
    // R4: unpinned -> compiler re-loaded from L2 every chunk (4.2GB, = the 137us).
    // R5: "+v" pin ate the whole VGPR pool and starved the loads (307us).
    // "+a": AGPR home; MFMA sources B from AGPR natively; VGPRs stay free.
    short8 wfr[4][8];
    {
        const unsigned short* wb = WtF + (((long)(proj * 8 + head) * 4) * 8) * 512 + (long)lane * 8;
        #pragma unroll
        for (int nt = 0; nt < 4; ++nt)
            #pragma unroll
            for (int ks = 0; ks < 8; ++ks)
                wfr[nt][ks] = *(const short8*)(wb + (nt * 8 + ks) * 512);
    }
    #pragma unroll
    for (int nt = 0; nt < 4; ++nt)
        #pragma unroll
        for (int ks = 0; ks < 8; ++ks)
            asm volatile("" : "+a"(wfr[nt][ks]));

    float bias[4];
    #pragma unroll
    for (int nt = 0; nt < 4; ++nt)
        bias[nt] = (proj == 0 ? bcv : bfx)[head * 64 + nt * 16 + l16];
    float tmp = temperature[head];
    tmp = fminf(fmaxf(tmp, 0.5f), 5.0f);
    const float invt = 1.0f / tmp;

    float4v Tac[4];
    #pragma unroll
    for (int nt = 0; nt < 4; ++nt) Tac[nt] = (float4v){0.f, 0.f, 0.f, 0.f};
    float normAcc[4] = {0.f, 0.f, 0.f, 0.f};

    // A-frag base: xf[(g32*2+tw)*4096 + lane*8 + ks*512], g32 = tile*16 + c
    const unsigned short* xb = xf + (((long)tile * 16 * 2 + tw) * 4096) + (long)lane * 8;
    short8 afr[8];
    #pragma unroll
    for (int ks = 0; ks < 8; ++ks)
        afr[ks] = *(const short8*)(xb + ks * 512);

    for (int c = 0; c < 16; ++c) {
        const int wbuf = c & 1, rbuf = wbuf ^ 1;

        // P1: [16 tok x 64 cols] += A(x) * B(w-AGPRs), K=256
        float4v acc[4];
        #pragma unroll
        for (int nt = 0; nt < 4; ++nt) acc[nt] = (float4v){0.f, 0.f, 0.f, 0.f};
        #pragma unroll
        for (int ks = 0; ks < 8; ++ks) {
            #pragma unroll
            for (int nt = 0; nt < 4; ++nt)
                acc[nt] = __builtin_amdgcn_mfma_f32_16x16x32_bf16(afr[ks], wfr[nt][ks], acc[nt], 0, 0, 0);
        }

        // prefetch next chunk's A-frags (hidden behind P3+P2+barrier)
        if (c < 15) {
            #pragma unroll
            for (int ks = 0; ks < 8; ++ks)
                afr[ks] = *(const short8*)(xb + (long)(c + 1) * 8192 + ks * 512);
        }

        // P3 (skewed): T[s][d] += w^T fx over PREVIOUS chunk's 32 tokens.
        if (c > 0) {
            short8 a = *(const short8*)(&wT[rbuf][(wv * 16 + l16) * MP + quad * 8]);
            #pragma unroll
            for (int nt = 0; nt < 4; ++nt) {
                short8 bf = *(const short8*)(&fT[rbuf][(nt * 16 + l16) * MP + quad * 8]);
                Tac[nt] = __builtin_amdgcn_mfma_f32_16x16x32_bf16(a, bf, Tac[nt], 0, 0, 0);
            }
        }

        // P2: softmax / bias -> transposed bf16 into wbuf.
        // C layout: col=l16+16*nt, row=quad*4+rr -> token = tw*16+quad*4+rr
        if (proj == 0) {
            float e[4][4];
            #pragma unroll
            for (int nt = 0; nt < 4; ++nt)
                #pragma unroll
                for (int rr = 0; rr < 4; ++rr)
                    e[nt][rr] = __expf((acc[nt][rr] + bias[nt]) * invt);  // bounded arg, shift-free
            #pragma unroll
            for (int rr = 0; rr < 4; ++rr) {
                float s = e[0][rr] + e[1][rr] + e[2][rr] + e[3][rr];
                s += __shfl_xor(s, 1); s += __shfl_xor(s, 2);
                s += __shfl_xor(s, 4); s += __shfl_xor(s, 8);
                float inv = 1.0f / s;
                e[0][rr] *= inv; e[1][rr] *= inv; e[2][rr] *= inv; e[3][rr] *= inv;
            }
            #pragma unroll
            for (int nt = 0; nt < 4; ++nt) {
                normAcc[nt] += e[nt][0] + e[nt][1] + e[nt][2] + e[nt][3];
                uint2v p;
                p.x = pack2(e[nt][0], e[nt][1]);
                p.y = pack2(e[nt][2], e[nt][3]);
                *(uint2v*)(&wT[wbuf][(nt * 16 + l16) * MP + tw * 16 + quad * 4]) = p;
            }
        } else {
            #pragma unroll
            for (int nt = 0; nt < 4; ++nt) {
                uint2v p;
                p.x = pack2(acc[nt][0] + bias[nt], acc[nt][1] + bias[nt]);
                p.y = pack2(acc[nt][2] + bias[nt], acc[nt][3] + bias[nt]);
                *(uint2v*)(&fT[wbuf][(nt * 16 + l16) * MP + tw * 16 + quad * 4]) = p;
            }
        }

        __syncthreads();   // single barrier per chunk
    }

    // final P3 on the last written buffer (chunk 15 -> buf 1)
    {
        short8 a = *(const short8*)(&wT[1][(wv * 16 + l16) * MP + quad * 8]);
        #pragma unroll
        for (int nt = 0; nt < 4; ++nt) {
            short8 bf = *(const short8*)(&fT[1][(nt * 16 + l16) * MP + quad * 8]);
            Tac[nt] = __builtin_amdgcn_mfma_f32_16x16x32_bf16(a, bf, Tac[nt], 0, 0, 0);
        }
    }

    // epilogue: atomics into global accumulators
    const int basehs = (batch * 8 + head) * 64;
    #pragma unroll
    for (int nt = 0; nt < 4; ++nt) {
        #pragma unroll
        for (int rr = 0; rr < 4; ++rr) {
            int s = wv * 16 + quad * 4 + rr;
            int d = nt * 16 + l16;
            atomicAdd(&Tg[(basehs + s) * 64 + d], Tac[nt][rr]);
        }
    }
    if (proj == 0) {
        #pragma unroll
        for (int nt = 0; nt < 4; ++nt) {
            float v = normAcc[nt];
            v += __shfl_xor(v, 16);
            v += __shfl_xor(v, 32);
            if (quad == 0) atomicAdd(&ng[basehs + nt * 16 + l16], v);
        }
    }
}

// ---------------- finalize ----------------
__global__ void msfe_final(const float* __restrict__ Tg, const float* __restrict__ ng,
                           float* __restrict__ out) {
    int i = blockIdx.x * 256 + threadIdx.x;
    out[i] = Tg[i] / (ng[i >> 6] + 0.01f);
}

extern "C" void kernel_launch(void* const* d_in, const int* in_sizes, int n_in,
                              void* d_out, int out_size, void* d_ws, size_t ws_size,
                              hipStream_t stream) {
    const float* x       = (const float*)d_in[0];
    const float* Wx      = (const float*)d_in[1];
    const float* bx      = (const float*)d_in[2];
    const float* Wfx     = (const float*)d_in[3];
    const float* bfx     = (const float*)d_in[4];
    const float* Wslice  = (const float*)d_in[5];
    const float* bslice  = (const float*)d_in[6];
    const float* temp    = (const float*)d_in[7];

    char* ws = (char*)d_ws;
    unsigned short* xf  = (unsigned short*)ws;               // 67,108,864 B
    unsigned short* WtF = (unsigned short*)(ws + 67108864);  //    524,288 B
    float* bc = (float*)(ws + 67633152);                     //      2,048 B
    float* Tg = (float*)(ws + 67635200);                     //    262,144 B
    float* ng = (float*)(ws + 67897344);                     //      4,096 B

    hipMemsetAsync(Tg, 0, 262144 + 4096, stream);   // ws re-poisoned 0xAA each call
    msfe_prep4<<<321, 256, 0, stream>>>(Wx, bx, Wfx, Wslice, bslice, WtF, bc);
    msfe_xprep<<<2048, 256, 0, stream>>>(x, xf);
    msfe_main5<<<2048, 256, 0, stream>>>(xf, WtF, bc, bfx, temp, Tg, ng);
    msfe_final<<<256, 256, 0, stream>>>(Tg, ng, (float*)d_out);
}